// Round 1
// baseline (211.485 us; speedup 1.0000x reference)
//
#include <hip/hip_runtime.h>

typedef short s16x8 __attribute__((ext_vector_type(8)));
typedef short s16x4 __attribute__((ext_vector_type(4)));
typedef float f32x4 __attribute__((ext_vector_type(4)));

#define SCALE_F 0.10206207261596577f  // 96^-0.5

__device__ __forceinline__ unsigned short f2bf(float f) {
  unsigned u = __builtin_bit_cast(unsigned, f);
  u += 0x7fffu + ((u >> 16) & 1u);
  return (unsigned short)(u >> 16);
}

#define MFMA16(a, b, c) __builtin_amdgcn_mfma_f32_16x16x32_bf16((a), (b), (c), 0, 0, 0)

// ---------------- fp32 -> bf16 convert (weights) ----------------
__global__ __launch_bounds__(256) void cvt_bf16_kernel(const float* __restrict__ src,
                                                       unsigned short* __restrict__ dst, int n4) {
  int i = blockIdx.x * 256 + threadIdx.x;
  if (i >= n4) return;
  f32x4 v = reinterpret_cast<const f32x4*>(src)[i];
  s16x4 o;
  o[0] = (short)f2bf(v[0]); o[1] = (short)f2bf(v[1]);
  o[2] = (short)f2bf(v[2]); o[3] = (short)f2bf(v[3]);
  reinterpret_cast<s16x4*>(dst)[i] = o;
}

// ---------------- x (B,C,N) -> tokens (B*N, C) bf16 ----------------
__global__ __launch_bounds__(256) void transpose_x_kernel(const float* __restrict__ x,
                                                          unsigned short* __restrict__ tokens) {
  __shared__ float t[32][33];
  const int ct = blockIdx.x * 32, nt = blockIdx.y * 32, b = blockIdx.z;
  const int tx = threadIdx.x, ty = threadIdx.y;
  const float* xp = x + (size_t)b * 768 * 1024;
#pragma unroll
  for (int r = 0; r < 4; ++r) {
    int c = ty + r * 8;
    t[c][tx] = xp[(size_t)(ct + c) * 1024 + nt + tx];
  }
  __syncthreads();
  unsigned short* tp = tokens + (size_t)b * 1024 * 768;
#pragma unroll
  for (int r = 0; r < 4; ++r) {
    int n = ty + r * 8;
    tp[(size_t)(nt + n) * 768 + ct + tx] = f2bf(t[tx][n]);
  }
}

// ---------------- QKV GEMM: tokens(8192x768) @ w_qkv^T(768x2304) ----------------
// A [M][K] bf16, Bt [N][K] bf16 (w_qkv rows contiguous in K).
// Writes Q,K as [b][h][n][96], V transposed as [b][h][96][n].
__global__ __launch_bounds__(256) void qkv_gemm_kernel(const unsigned short* __restrict__ A,
                                                       const unsigned short* __restrict__ Bt,
                                                       unsigned short* __restrict__ Qo,
                                                       unsigned short* __restrict__ Ko,
                                                       unsigned short* __restrict__ Vt) {
  __shared__ unsigned short As[128][48];
  __shared__ unsigned short Bs[128][48];
  const int tid = threadIdx.x;
  const int wave = tid >> 6, lane = tid & 63;
  const int wr = wave >> 1, wc = wave & 1;
  const int lr = lane & 15, lg = lane >> 4;
  const int m0 = blockIdx.y * 128, n0 = blockIdx.x * 128;

  f32x4 acc[4][4] = {};

  const int r0 = tid >> 2, k80 = (tid & 3) * 8;
  const int c1 = tid + 256;
  const int r1 = c1 >> 2, k81 = (c1 & 3) * 8;

  for (int kt = 0; kt < 768; kt += 32) {
    s16x8 a0 = *reinterpret_cast<const s16x8*>(A + (size_t)(m0 + r0) * 768 + kt + k80);
    s16x8 a1 = *reinterpret_cast<const s16x8*>(A + (size_t)(m0 + r1) * 768 + kt + k81);
    s16x8 b0 = *reinterpret_cast<const s16x8*>(Bt + (size_t)(n0 + r0) * 768 + kt + k80);
    s16x8 b1 = *reinterpret_cast<const s16x8*>(Bt + (size_t)(n0 + r1) * 768 + kt + k81);
    __syncthreads();
    *reinterpret_cast<s16x8*>(&As[r0][k80]) = a0;
    *reinterpret_cast<s16x8*>(&As[r1][k81]) = a1;
    *reinterpret_cast<s16x8*>(&Bs[r0][k80]) = b0;
    *reinterpret_cast<s16x8*>(&Bs[r1][k81]) = b1;
    __syncthreads();
    s16x8 af[4], bf[4];
#pragma unroll
    for (int mi = 0; mi < 4; ++mi)
      af[mi] = *reinterpret_cast<const s16x8*>(&As[wr * 64 + mi * 16 + lr][lg * 8]);
#pragma unroll
    for (int ni = 0; ni < 4; ++ni)
      bf[ni] = *reinterpret_cast<const s16x8*>(&Bs[wc * 64 + ni * 16 + lr][lg * 8]);
#pragma unroll
    for (int mi = 0; mi < 4; ++mi)
#pragma unroll
      for (int ni = 0; ni < 4; ++ni)
        acc[mi][ni] = MFMA16(af[mi], bf[ni], acc[mi][ni]);
  }

#pragma unroll
  for (int ni = 0; ni < 4; ++ni) {
    const int col = n0 + wc * 64 + ni * 16 + lr;   // 0..2303
    const int t = col / 768;
    const int cc = col - t * 768;
    const int h = cc / 96;
    const int d = cc - h * 96;
#pragma unroll
    for (int mi = 0; mi < 4; ++mi) {
      const int gm = m0 + wr * 64 + mi * 16 + lg * 4;
      const int b = gm >> 10, n = gm & 1023;
      if (t == 2) {
        s16x4 v;
#pragma unroll
        for (int j = 0; j < 4; ++j) v[j] = (short)f2bf(acc[mi][ni][j]);
        *reinterpret_cast<s16x4*>(Vt + ((size_t)(b * 8 + h) * 96 + d) * 1024 + n) = v;
      } else {
        unsigned short* dst = (t == 0) ? Qo : Ko;
#pragma unroll
        for (int j = 0; j < 4; ++j)
          dst[((size_t)(b * 8 + h) * 1024 + n + j) * 96 + d] = f2bf(acc[mi][ni][j]);
      }
    }
  }
}

// ---------------- flash attention: per block one (b,h) x 64 q-rows ----------------
__global__ __launch_bounds__(256) void attn_kernel(const unsigned short* __restrict__ Q,
                                                   const unsigned short* __restrict__ K,
                                                   const unsigned short* __restrict__ Vt,
                                                   unsigned short* __restrict__ Ao) {
  const int bh = blockIdx.y;  // b*8+h
  const int qb = blockIdx.x;  // 0..15
  const unsigned short* Qp = Q + (size_t)bh * 1024 * 96;
  const unsigned short* Kp = K + (size_t)bh * 1024 * 96;
  const unsigned short* Vp = Vt + (size_t)bh * 96 * 1024;

  __shared__ unsigned short Qs[64][104];
  __shared__ unsigned short Ks[128][104];
  __shared__ unsigned short Vs[96][136];   // [d][kv]
  __shared__ float Sb[64][132];
  __shared__ unsigned short Pb[64][136];
  __shared__ float rowM[64], rowL[64], rowSc[64];

  const int tid = threadIdx.x, wave = tid >> 6, lane = tid & 63;
  const int lr = lane & 15, lg = lane >> 4;

  // load Q block (64x96): 768 16B chunks
#pragma unroll
  for (int i = 0; i < 3; ++i) {
    int c = tid + i * 256;
    int row = c / 12, k8 = (c % 12) * 8;
    *reinterpret_cast<s16x8*>(&Qs[row][k8]) =
        *reinterpret_cast<const s16x8*>(Qp + (size_t)(qb * 64 + row) * 96 + k8);
  }
  if (tid < 64) { rowM[tid] = -1e30f; rowL[tid] = 0.f; }

  f32x4 oacc[6] = {};

  for (int kt = 0; kt < 8; ++kt) {
    __syncthreads();  // prior PV reads done (1st iter: Q load + rowM init visible)
    // K tile 128x96
#pragma unroll
    for (int i = 0; i < 6; ++i) {
      int c = tid + i * 256;
      int row = c / 12, k8 = (c % 12) * 8;
      *reinterpret_cast<s16x8*>(&Ks[row][k8]) =
          *reinterpret_cast<const s16x8*>(Kp + (size_t)(kt * 128 + row) * 96 + k8);
    }
    // V tile (transposed source): 96 x 128
#pragma unroll
    for (int i = 0; i < 6; ++i) {
      int c = tid + i * 256;
      int d = c / 16, k8 = (c % 16) * 8;
      *reinterpret_cast<s16x8*>(&Vs[d][k8]) =
          *reinterpret_cast<const s16x8*>(Vp + (size_t)d * 1024 + kt * 128 + k8);
    }
    __syncthreads();

    // S = Q K^T  (wave's 16 q-rows x 128 kv)
    f32x4 sacc[8] = {};
#pragma unroll
    for (int kd = 0; kd < 3; ++kd) {
      s16x8 aq = *reinterpret_cast<const s16x8*>(&Qs[wave * 16 + lr][kd * 32 + lg * 8]);
#pragma unroll
      for (int c = 0; c < 8; ++c) {
        s16x8 bk = *reinterpret_cast<const s16x8*>(&Ks[c * 16 + lr][kd * 32 + lg * 8]);
        sacc[c] = MFMA16(aq, bk, sacc[c]);
      }
    }
#pragma unroll
    for (int c = 0; c < 8; ++c)
#pragma unroll
      for (int j = 0; j < 4; ++j)
        Sb[wave * 16 + lg * 4 + j][c * 16 + lr] = sacc[c][j] * SCALE_F;
    __syncthreads();

    // softmax: 4 threads per row, strided columns (bank-clean)
    {
      const int row = tid >> 2, slot = tid & 3;
      float mx = -1e30f;
#pragma unroll
      for (int i = 0; i < 32; ++i) mx = fmaxf(mx, Sb[row][slot + 4 * i]);
      mx = fmaxf(mx, __shfl_xor(mx, 1));
      mx = fmaxf(mx, __shfl_xor(mx, 2));
      const float mOld = rowM[row];
      const float mNew = fmaxf(mOld, mx);
      float sum = 0.f;
#pragma unroll
      for (int i = 0; i < 32; ++i) {
        int c = slot + 4 * i;
        float p = __expf(Sb[row][c] - mNew);
        sum += p;
        Pb[row][c] = f2bf(p);
      }
      sum += __shfl_xor(sum, 1);
      sum += __shfl_xor(sum, 2);
      if (slot == 0) {
        float sc = __expf(mOld - mNew);
        rowSc[row] = sc;
        rowL[row] = rowL[row] * sc + sum;
        rowM[row] = mNew;
      }
    }
    __syncthreads();

    // rescale O, then O += P V
    float rs[4];
#pragma unroll
    for (int j = 0; j < 4; ++j) rs[j] = rowSc[wave * 16 + lg * 4 + j];
#pragma unroll
    for (int c = 0; c < 6; ++c)
#pragma unroll
      for (int j = 0; j < 4; ++j) oacc[c][j] *= rs[j];
#pragma unroll
    for (int ks = 0; ks < 4; ++ks) {
      s16x8 ap = *reinterpret_cast<const s16x8*>(&Pb[wave * 16 + lr][ks * 32 + lg * 8]);
#pragma unroll
      for (int c = 0; c < 6; ++c) {
        s16x8 bv = *reinterpret_cast<const s16x8*>(&Vs[c * 16 + lr][ks * 32 + lg * 8]);
        oacc[c] = MFMA16(ap, bv, oacc[c]);
      }
    }
  }

  float invl[4];
#pragma unroll
  for (int j = 0; j < 4; ++j) invl[j] = 1.0f / rowL[wave * 16 + lg * 4 + j];
  const int b = bh >> 3, h = bh & 7;
#pragma unroll
  for (int c = 0; c < 6; ++c)
#pragma unroll
    for (int j = 0; j < 4; ++j) {
      int row = qb * 64 + wave * 16 + lg * 4 + j;
      int col = h * 96 + c * 16 + lr;
      Ao[(size_t)(b * 1024 + row) * 768 + col] = f2bf(oacc[c][j] * invl[j]);
    }
}

// ---------------- proj GEMM: attn(8192x768) @ w_proj^T + b, store transposed ----------------
__global__ __launch_bounds__(256) void proj_gemm_kernel(const unsigned short* __restrict__ A,
                                                        const unsigned short* __restrict__ Bt,
                                                        const float* __restrict__ bias,
                                                        float* __restrict__ out) {
  __shared__ unsigned short As[128][48];
  __shared__ unsigned short Bs[128][48];
  const int tid = threadIdx.x;
  const int wave = tid >> 6, lane = tid & 63;
  const int wr = wave >> 1, wc = wave & 1;
  const int lr = lane & 15, lg = lane >> 4;
  const int m0 = blockIdx.y * 128, n0 = blockIdx.x * 128;

  f32x4 acc[4][4] = {};

  const int r0 = tid >> 2, k80 = (tid & 3) * 8;
  const int c1 = tid + 256;
  const int r1 = c1 >> 2, k81 = (c1 & 3) * 8;

  for (int kt = 0; kt < 768; kt += 32) {
    s16x8 a0 = *reinterpret_cast<const s16x8*>(A + (size_t)(m0 + r0) * 768 + kt + k80);
    s16x8 a1 = *reinterpret_cast<const s16x8*>(A + (size_t)(m0 + r1) * 768 + kt + k81);
    s16x8 b0 = *reinterpret_cast<const s16x8*>(Bt + (size_t)(n0 + r0) * 768 + kt + k80);
    s16x8 b1 = *reinterpret_cast<const s16x8*>(Bt + (size_t)(n0 + r1) * 768 + kt + k81);
    __syncthreads();
    *reinterpret_cast<s16x8*>(&As[r0][k80]) = a0;
    *reinterpret_cast<s16x8*>(&As[r1][k81]) = a1;
    *reinterpret_cast<s16x8*>(&Bs[r0][k80]) = b0;
    *reinterpret_cast<s16x8*>(&Bs[r1][k81]) = b1;
    __syncthreads();
    s16x8 af[4], bf[4];
#pragma unroll
    for (int mi = 0; mi < 4; ++mi)
      af[mi] = *reinterpret_cast<const s16x8*>(&As[wr * 64 + mi * 16 + lr][lg * 8]);
#pragma unroll
    for (int ni = 0; ni < 4; ++ni)
      bf[ni] = *reinterpret_cast<const s16x8*>(&Bs[wc * 64 + ni * 16 + lr][lg * 8]);
#pragma unroll
    for (int mi = 0; mi < 4; ++mi)
#pragma unroll
      for (int ni = 0; ni < 4; ++ni)
        acc[mi][ni] = MFMA16(af[mi], bf[ni], acc[mi][ni]);
  }

#pragma unroll
  for (int ni = 0; ni < 4; ++ni) {
    const int col = n0 + wc * 64 + ni * 16 + lr;  // c: 0..767
    const float bv = bias[col];
#pragma unroll
    for (int mi = 0; mi < 4; ++mi) {
      const int gm = m0 + wr * 64 + mi * 16 + lg * 4;
      const int b = gm >> 10, n = gm & 1023;
      f32x4 v;
#pragma unroll
      for (int j = 0; j < 4; ++j) v[j] = acc[mi][ni][j] + bv;
      *reinterpret_cast<f32x4*>(out + (size_t)b * 768 * 1024 + (size_t)col * 1024 + n) = v;
    }
  }
}

extern "C" void kernel_launch(void* const* d_in, const int* in_sizes, int n_in,
                              void* d_out, int out_size, void* d_ws, size_t ws_size,
                              hipStream_t stream) {
  const float* x = (const float*)d_in[0];
  const float* wqkv = (const float*)d_in[1];
  const float* wproj = (const float*)d_in[2];
  const float* bproj = (const float*)d_in[3];
  float* out = (float*)d_out;

  unsigned short* ws = (unsigned short*)d_ws;
  unsigned short* tokens = ws;                       // 8192*768
  unsigned short* wqkv_b = tokens + 8192 * 768;      // 2304*768
  unsigned short* wproj_b = wqkv_b + 2304 * 768;     // 768*768
  unsigned short* Qb = wproj_b + 768 * 768;          // 64*1024*96
  unsigned short* Kb = Qb + 64 * 1024 * 96;
  unsigned short* Vb = Kb + 64 * 1024 * 96;          // transposed [b][h][96][1024]
  unsigned short* Ab = Vb + 64 * 1024 * 96;          // 8192*768

  cvt_bf16_kernel<<<1728, 256, 0, stream>>>(wqkv, wqkv_b, 2304 * 768 / 4);
  cvt_bf16_kernel<<<576, 256, 0, stream>>>(wproj, wproj_b, 768 * 768 / 4);
  transpose_x_kernel<<<dim3(24, 32, 8), dim3(32, 8), 0, stream>>>(x, tokens);
  qkv_gemm_kernel<<<dim3(18, 64), 256, 0, stream>>>(tokens, wqkv_b, Qb, Kb, Vb);
  attn_kernel<<<dim3(16, 64), 256, 0, stream>>>(Qb, Kb, Vb, Ab);
  proj_gemm_kernel<<<dim3(6, 64), 256, 0, stream>>>(Ab, wproj_b, bproj, out);
}

// Round 2
// 153.082 us; speedup vs baseline: 1.3815x; 1.3815x over previous
//
#include <hip/hip_runtime.h>

typedef short s16x8 __attribute__((ext_vector_type(8)));
typedef short s16x4 __attribute__((ext_vector_type(4)));
typedef float f32x4 __attribute__((ext_vector_type(4)));
typedef int   i32x4 __attribute__((ext_vector_type(4)));

#define SCALE_F 0.10206207261596577f  // 96^-0.5

__device__ __forceinline__ unsigned short f2bf(float f) {
  unsigned u = __builtin_bit_cast(unsigned, f);
  u += 0x7fffu + ((u >> 16) & 1u);
  return (unsigned short)(u >> 16);
}
__device__ __forceinline__ unsigned pack_bf2(float a, float b) {
  return (unsigned)f2bf(a) | ((unsigned)f2bf(b) << 16);
}

#define MFMA16(a, b, c) __builtin_amdgcn_mfma_f32_16x16x32_bf16((a), (b), (c), 0, 0, 0)

// async global->LDS, 16B per lane; lds dest must be wave-uniform base (+lane*16 by HW)
__device__ __forceinline__ void gl_lds16(const unsigned short* g, unsigned short* l) {
  __builtin_amdgcn_global_load_lds(
      (const __attribute__((address_space(1))) void*)g,
      (__attribute__((address_space(3))) void*)l, 16, 0, 0);
}

// ---------------- fp32 -> bf16 convert (weights) ----------------
__global__ __launch_bounds__(256) void cvt_bf16_kernel(const float* __restrict__ src,
                                                       unsigned short* __restrict__ dst, int n4) {
  int i = blockIdx.x * 256 + threadIdx.x;
  if (i >= n4) return;
  f32x4 v = reinterpret_cast<const f32x4*>(src)[i];
  s16x4 o;
  o[0] = (short)f2bf(v[0]); o[1] = (short)f2bf(v[1]);
  o[2] = (short)f2bf(v[2]); o[3] = (short)f2bf(v[3]);
  reinterpret_cast<s16x4*>(dst)[i] = o;
}

// ---------------- x (B,C,N) -> tokens (B*N, C) bf16 ----------------
__global__ __launch_bounds__(256) void transpose_x_kernel(const float* __restrict__ x,
                                                          unsigned short* __restrict__ tokens) {
  __shared__ float t[32][33];
  const int ct = blockIdx.x * 32, nt = blockIdx.y * 32, b = blockIdx.z;
  const int tx = threadIdx.x, ty = threadIdx.y;
  const float* xp = x + (size_t)b * 768 * 1024;
#pragma unroll
  for (int r = 0; r < 4; ++r) {
    int c = ty + r * 8;
    t[c][tx] = xp[(size_t)(ct + c) * 1024 + nt + tx];
  }
  __syncthreads();
  unsigned short* tp = tokens + (size_t)b * 1024 * 768;
#pragma unroll
  for (int r = 0; r < 4; ++r) {
    int n = ty + r * 8;
    tp[(size_t)(nt + n) * 768 + ct + tx] = f2bf(t[tx][n]);
  }
}

// ---------------- QKV GEMM: tokens(8192x768) @ w_qkv^T(768x2304) ----------------
__global__ __launch_bounds__(256) void qkv_gemm_kernel(const unsigned short* __restrict__ A,
                                                       const unsigned short* __restrict__ Bt,
                                                       unsigned short* __restrict__ Qo,
                                                       unsigned short* __restrict__ Ko,
                                                       unsigned short* __restrict__ Vt) {
  __shared__ unsigned short As[128][48];
  __shared__ unsigned short Bs[128][48];
  const int tid = threadIdx.x;
  const int wave = tid >> 6, lane = tid & 63;
  const int wr = wave >> 1, wc = wave & 1;
  const int lr = lane & 15, lg = lane >> 4;
  const int m0 = blockIdx.y * 128, n0 = blockIdx.x * 128;

  f32x4 acc[4][4] = {};

  const int r0 = tid >> 2, k80 = (tid & 3) * 8;
  const int c1 = tid + 256;
  const int r1 = c1 >> 2, k81 = (c1 & 3) * 8;

  for (int kt = 0; kt < 768; kt += 32) {
    s16x8 a0 = *reinterpret_cast<const s16x8*>(A + (size_t)(m0 + r0) * 768 + kt + k80);
    s16x8 a1 = *reinterpret_cast<const s16x8*>(A + (size_t)(m0 + r1) * 768 + kt + k81);
    s16x8 b0 = *reinterpret_cast<const s16x8*>(Bt + (size_t)(n0 + r0) * 768 + kt + k80);
    s16x8 b1 = *reinterpret_cast<const s16x8*>(Bt + (size_t)(n0 + r1) * 768 + kt + k81);
    __syncthreads();
    *reinterpret_cast<s16x8*>(&As[r0][k80]) = a0;
    *reinterpret_cast<s16x8*>(&As[r1][k81]) = a1;
    *reinterpret_cast<s16x8*>(&Bs[r0][k80]) = b0;
    *reinterpret_cast<s16x8*>(&Bs[r1][k81]) = b1;
    __syncthreads();
    s16x8 af[4], bf[4];
#pragma unroll
    for (int mi = 0; mi < 4; ++mi)
      af[mi] = *reinterpret_cast<const s16x8*>(&As[wr * 64 + mi * 16 + lr][lg * 8]);
#pragma unroll
    for (int ni = 0; ni < 4; ++ni)
      bf[ni] = *reinterpret_cast<const s16x8*>(&Bs[wc * 64 + ni * 16 + lr][lg * 8]);
#pragma unroll
    for (int mi = 0; mi < 4; ++mi)
#pragma unroll
      for (int ni = 0; ni < 4; ++ni)
        acc[mi][ni] = MFMA16(af[mi], bf[ni], acc[mi][ni]);
  }

#pragma unroll
  for (int ni = 0; ni < 4; ++ni) {
    const int col = n0 + wc * 64 + ni * 16 + lr;   // 0..2303
    const int t = col / 768;
    const int cc = col - t * 768;
    const int h = cc / 96;
    const int d = cc - h * 96;
#pragma unroll
    for (int mi = 0; mi < 4; ++mi) {
      const int gm = m0 + wr * 64 + mi * 16 + lg * 4;
      const int b = gm >> 10, n = gm & 1023;
      if (t == 2) {
        s16x4 v;
#pragma unroll
        for (int j = 0; j < 4; ++j) v[j] = (short)f2bf(acc[mi][ni][j]);
        *reinterpret_cast<s16x4*>(Vt + ((size_t)(b * 8 + h) * 96 + d) * 1024 + n) = v;
      } else {
        unsigned short* dst = (t == 0) ? Qo : Ko;
#pragma unroll
        for (int j = 0; j < 4; ++j)
          dst[((size_t)(b * 8 + h) * 1024 + n + j) * 96 + d] = f2bf(acc[mi][ni][j]);
      }
    }
  }
}

// ---------------- flash attention, in-register softmax ----------------
// block: 512 thr = 8 waves, each wave 16 q rows (128 q / block); KVB=64 double-buffered.
// S^T = mfma(Kfrag, Qfrag): lane(lr,lg) holds S^T[kv=16c+lg*4+j][q=lr] -> softmax over kv is
// in-lane + shfl_xor(16/32). P^T redistributed to B-operand layout via 8 shuffles / 32 kv.
__global__ __launch_bounds__(512, 4) void attn_kernel(const unsigned short* __restrict__ Q,
                                                      const unsigned short* __restrict__ K,
                                                      const unsigned short* __restrict__ Vt,
                                                      unsigned short* __restrict__ Ao) {
  __shared__ unsigned short Ks[2][64][128];  // K rows padded 96->128 for XOR swizzle
  __shared__ unsigned short Vs[2][96][64];   // V^T rows: 64 kv = 8 slots

  const int f = blockIdx.x;
  const int xcd = f & 7;
  const int g = (f >> 3) + xcd * 64;   // same-bh blocks land on same XCD
  const int bh = g >> 3, qb = g & 7;

  const int tid = threadIdx.x, wave = tid >> 6, lane = tid & 63;
  const int lr = lane & 15, lg = lane >> 4;
  const int sw = lr & 7;  // read-side XOR swizzle key (row&7 == lr&7 for 16-strided rows)

  const unsigned short* Qp = Q + (size_t)bh * 1024 * 96;
  const unsigned short* Kp = K + (size_t)bh * 1024 * 96;
  const unsigned short* Vp = Vt + (size_t)bh * 96 * 1024;

  // Q fragments in registers (reused for all KV tiles)
  const int qrow = qb * 128 + wave * 16 + lr;
  s16x8 qreg[3];
#pragma unroll
  for (int kd = 0; kd < 3; ++kd)
    qreg[kd] = *reinterpret_cast<const s16x8*>(Qp + (size_t)qrow * 96 + kd * 32 + lg * 8);

  float m_r = -1e30f, l_r = 0.f;
  f32x4 oacc[6] = {};

  const int srcA = lr + ((lg & 1) << 5);   // shuffle sources for P^T redistribution
  const int srcB = srcA + 16;
  const bool hiT = (lg & 2) != 0;

#define STAGE(bufi, kv0)                                                              \
  {                                                                                   \
    _Pragma("unroll")                                                                 \
    for (int i = 0; i < 4; ++i) {                                                     \
      int cc = wave + 8 * i;                                                          \
      if (cc < 16) {                                                                  \
        int c = cc * 64 + lane;                                                       \
        int row = c >> 4, s = c & 15;                                                 \
        int sp = s ^ (row & 7);                                                       \
        if (sp > 11) sp = 11; /* pad slot, never read */                              \
        gl_lds16(Kp + (size_t)((kv0) + row) * 96 + sp * 8,                            \
                 &Ks[bufi][0][0] + cc * 512);                                         \
      } else if (cc < 28) {                                                           \
        int vc = cc - 16;                                                             \
        int c = vc * 64 + lane;                                                       \
        int row = c >> 3, s = c & 7;                                                  \
        int sp = s ^ (row & 7);                                                       \
        gl_lds16(Vp + (size_t)row * 1024 + (kv0) + sp * 8,                            \
                 &Vs[bufi][0][0] + vc * 512);                                         \
      }                                                                               \
    }                                                                                 \
  }

  STAGE(0, 0);
  __syncthreads();

  for (int gt = 0; gt < 16; ++gt) {
    const int buf = gt & 1;
    if (gt < 15) STAGE(buf ^ 1, (gt + 1) * 64);

    // ---- S^T = K Q^T over this 64-kv group ----
    f32x4 sacc[4] = {};
#pragma unroll
    for (int c = 0; c < 4; ++c) {
#pragma unroll
      for (int kd = 0; kd < 3; ++kd) {
        s16x8 kf = *reinterpret_cast<const s16x8*>(&Ks[buf][c * 16 + lr][((kd * 4 + lg) ^ sw) * 8]);
        sacc[c] = MFMA16(kf, qreg[kd], sacc[c]);
      }
    }

    // ---- online softmax (in-register; q = lr, kv lane-local) ----
    float mx = -1e30f;
#pragma unroll
    for (int c = 0; c < 4; ++c) {
#pragma unroll
      for (int j = 0; j < 4; ++j) {
        sacc[c][j] *= SCALE_F;
        mx = fmaxf(mx, sacc[c][j]);
      }
    }
    mx = fmaxf(mx, __shfl_xor(mx, 16));
    mx = fmaxf(mx, __shfl_xor(mx, 32));
    const float mNew = fmaxf(m_r, mx);
    const float rsc = __expf(m_r - mNew);
    float ts = 0.f;
    unsigned pk[4][2];
#pragma unroll
    for (int c = 0; c < 4; ++c) {
      float p0 = __expf(sacc[c][0] - mNew);
      float p1 = __expf(sacc[c][1] - mNew);
      float p2 = __expf(sacc[c][2] - mNew);
      float p3 = __expf(sacc[c][3] - mNew);
      ts += (p0 + p1) + (p2 + p3);
      pk[c][0] = pack_bf2(p0, p1);
      pk[c][1] = pack_bf2(p2, p3);
    }
    ts += __shfl_xor(ts, 16);
    ts += __shfl_xor(ts, 32);
    l_r = l_r * rsc + ts;
    m_r = mNew;
#pragma unroll
    for (int dt = 0; dt < 6; ++dt) oacc[dt] *= rsc;

    // ---- O^T += V^T P^T ----
#pragma unroll
    for (int gs = 0; gs < 2; ++gs) {
      const int t0 = gs * 2, t1 = t0 + 1;
      int la0 = __shfl((int)pk[t0][0], srcA), la1 = __shfl((int)pk[t1][0], srcA);
      int ha0 = __shfl((int)pk[t0][1], srcA), ha1 = __shfl((int)pk[t1][1], srcA);
      int lb0 = __shfl((int)pk[t0][0], srcB), lb1 = __shfl((int)pk[t1][0], srcB);
      int hb0 = __shfl((int)pk[t0][1], srcB), hb1 = __shfl((int)pk[t1][1], srcB);
      i32x4 bi;
      bi[0] = hiT ? la1 : la0;
      bi[1] = hiT ? ha1 : ha0;
      bi[2] = hiT ? lb1 : lb0;
      bi[3] = hiT ? hb1 : hb0;
      s16x8 pf = __builtin_bit_cast(s16x8, bi);
#pragma unroll
      for (int dt = 0; dt < 6; ++dt) {
        s16x8 vf = *reinterpret_cast<const s16x8*>(&Vs[buf][dt * 16 + lr][((gs * 4 + lg) ^ sw) * 8]);
        oacc[dt] = MFMA16(vf, pf, oacc[dt]);
      }
    }
    __syncthreads();  // drains staged loads; buffer swap safe
  }

  const float invl = 1.0f / l_r;
  const int b_ = bh >> 3, h_ = bh & 7;
  unsigned short* orow = Ao + (size_t)(b_ * 1024 + qrow) * 768 + h_ * 96;
#pragma unroll
  for (int dt = 0; dt < 6; ++dt) {
    s16x4 o4;
#pragma unroll
    for (int j = 0; j < 4; ++j) o4[j] = (short)f2bf(oacc[dt][j] * invl);
    *reinterpret_cast<s16x4*>(orow + dt * 16 + lg * 4) = o4;
  }
#undef STAGE
}

// ---------------- proj GEMM: attn(8192x768) @ w_proj^T + b, store transposed ----------------
__global__ __launch_bounds__(256) void proj_gemm_kernel(const unsigned short* __restrict__ A,
                                                        const unsigned short* __restrict__ Bt,
                                                        const float* __restrict__ bias,
                                                        float* __restrict__ out) {
  __shared__ unsigned short As[128][48];
  __shared__ unsigned short Bs[128][48];
  const int tid = threadIdx.x;
  const int wave = tid >> 6, lane = tid & 63;
  const int wr = wave >> 1, wc = wave & 1;
  const int lr = lane & 15, lg = lane >> 4;
  const int m0 = blockIdx.y * 128, n0 = blockIdx.x * 128;

  f32x4 acc[4][4] = {};

  const int r0 = tid >> 2, k80 = (tid & 3) * 8;
  const int c1 = tid + 256;
  const int r1 = c1 >> 2, k81 = (c1 & 3) * 8;

  for (int kt = 0; kt < 768; kt += 32) {
    s16x8 a0 = *reinterpret_cast<const s16x8*>(A + (size_t)(m0 + r0) * 768 + kt + k80);
    s16x8 a1 = *reinterpret_cast<const s16x8*>(A + (size_t)(m0 + r1) * 768 + kt + k81);
    s16x8 b0 = *reinterpret_cast<const s16x8*>(Bt + (size_t)(n0 + r0) * 768 + kt + k80);
    s16x8 b1 = *reinterpret_cast<const s16x8*>(Bt + (size_t)(n0 + r1) * 768 + kt + k81);
    __syncthreads();
    *reinterpret_cast<s16x8*>(&As[r0][k80]) = a0;
    *reinterpret_cast<s16x8*>(&As[r1][k81]) = a1;
    *reinterpret_cast<s16x8*>(&Bs[r0][k80]) = b0;
    *reinterpret_cast<s16x8*>(&Bs[r1][k81]) = b1;
    __syncthreads();
    s16x8 af[4], bf[4];
#pragma unroll
    for (int mi = 0; mi < 4; ++mi)
      af[mi] = *reinterpret_cast<const s16x8*>(&As[wr * 64 + mi * 16 + lr][lg * 8]);
#pragma unroll
    for (int ni = 0; ni < 4; ++ni)
      bf[ni] = *reinterpret_cast<const s16x8*>(&Bs[wc * 64 + ni * 16 + lr][lg * 8]);
#pragma unroll
    for (int mi = 0; mi < 4; ++mi)
#pragma unroll
      for (int ni = 0; ni < 4; ++ni)
        acc[mi][ni] = MFMA16(af[mi], bf[ni], acc[mi][ni]);
  }

#pragma unroll
  for (int ni = 0; ni < 4; ++ni) {
    const int col = n0 + wc * 64 + ni * 16 + lr;  // c: 0..767
    const float bv = bias[col];
#pragma unroll
    for (int mi = 0; mi < 4; ++mi) {
      const int gm = m0 + wr * 64 + mi * 16 + lg * 4;
      const int b = gm >> 10, n = gm & 1023;
      f32x4 v;
#pragma unroll
      for (int j = 0; j < 4; ++j) v[j] = acc[mi][ni][j] + bv;
      *reinterpret_cast<f32x4*>(out + (size_t)b * 768 * 1024 + (size_t)col * 1024 + n) = v;
    }
  }
}

extern "C" void kernel_launch(void* const* d_in, const int* in_sizes, int n_in,
                              void* d_out, int out_size, void* d_ws, size_t ws_size,
                              hipStream_t stream) {
  const float* x = (const float*)d_in[0];
  const float* wqkv = (const float*)d_in[1];
  const float* wproj = (const float*)d_in[2];
  const float* bproj = (const float*)d_in[3];
  float* out = (float*)d_out;

  unsigned short* ws = (unsigned short*)d_ws;
  unsigned short* tokens = ws;                       // 8192*768
  unsigned short* wqkv_b = tokens + 8192 * 768;      // 2304*768
  unsigned short* wproj_b = wqkv_b + 2304 * 768;     // 768*768
  unsigned short* Qb = wproj_b + 768 * 768;          // [bh][1024][96]
  unsigned short* Kb = Qb + 64 * 1024 * 96;
  unsigned short* Vb = Kb + 64 * 1024 * 96;          // transposed [bh][96][1024]
  unsigned short* Ab = Vb + 64 * 1024 * 96;          // 8192*768

  cvt_bf16_kernel<<<1728, 256, 0, stream>>>(wqkv, wqkv_b, 2304 * 768 / 4);
  cvt_bf16_kernel<<<576, 256, 0, stream>>>(wproj, wproj_b, 768 * 768 / 4);
  transpose_x_kernel<<<dim3(24, 32, 8), dim3(32, 8), 0, stream>>>(x, tokens);
  qkv_gemm_kernel<<<dim3(18, 64), 256, 0, stream>>>(tokens, wqkv_b, Qb, Kb, Vb);
  attn_kernel<<<512, 512, 0, stream>>>(Qb, Kb, Vb, Ab);
  proj_gemm_kernel<<<dim3(6, 64), 256, 0, stream>>>(Ab, wproj_b, bproj, out);
}

// Round 3
// 152.904 us; speedup vs baseline: 1.3831x; 1.0012x over previous
//
#include <hip/hip_runtime.h>

typedef short s16x8 __attribute__((ext_vector_type(8)));
typedef short s16x4 __attribute__((ext_vector_type(4)));
typedef float f32x4 __attribute__((ext_vector_type(4)));
typedef int   i32x4 __attribute__((ext_vector_type(4)));

#define SCALE_F 0.10206207261596577f  // 96^-0.5

__device__ __forceinline__ unsigned short f2bf(float f) {
  unsigned u = __builtin_bit_cast(unsigned, f);
  u += 0x7fffu + ((u >> 16) & 1u);
  return (unsigned short)(u >> 16);
}
__device__ __forceinline__ unsigned pack_bf2(float a, float b) {
  return (unsigned)f2bf(a) | ((unsigned)f2bf(b) << 16);
}

#define MFMA16(a, b, c) __builtin_amdgcn_mfma_f32_16x16x32_bf16((a), (b), (c), 0, 0, 0)

// async global->LDS, 16B per lane; lds dest must be wave-uniform base (+lane*16 by HW)
__device__ __forceinline__ void gl_lds16(const unsigned short* g, unsigned short* l) {
  __builtin_amdgcn_global_load_lds(
      (const __attribute__((address_space(1))) void*)g,
      (__attribute__((address_space(3))) void*)l, 16, 0, 0);
}

// ---------------- fp32 -> bf16 convert (weights) ----------------
__global__ __launch_bounds__(256) void cvt_bf16_kernel(const float* __restrict__ src,
                                                       unsigned short* __restrict__ dst, int n4) {
  int i = blockIdx.x * 256 + threadIdx.x;
  if (i >= n4) return;
  f32x4 v = reinterpret_cast<const f32x4*>(src)[i];
  s16x4 o;
  o[0] = (short)f2bf(v[0]); o[1] = (short)f2bf(v[1]);
  o[2] = (short)f2bf(v[2]); o[3] = (short)f2bf(v[3]);
  reinterpret_cast<s16x4*>(dst)[i] = o;
}

// ---------------- x (B,C,N) -> tokens (B*N, C) bf16 ----------------
__global__ __launch_bounds__(256) void transpose_x_kernel(const float* __restrict__ x,
                                                          unsigned short* __restrict__ tokens) {
  __shared__ float t[32][33];
  const int ct = blockIdx.x * 32, nt = blockIdx.y * 32, b = blockIdx.z;
  const int tx = threadIdx.x, ty = threadIdx.y;
  const float* xp = x + (size_t)b * 768 * 1024;
#pragma unroll
  for (int r = 0; r < 4; ++r) {
    int c = ty + r * 8;
    t[c][tx] = xp[(size_t)(ct + c) * 1024 + nt + tx];
  }
  __syncthreads();
  unsigned short* tp = tokens + (size_t)b * 1024 * 768;
#pragma unroll
  for (int r = 0; r < 4; ++r) {
    int n = ty + r * 8;
    tp[(size_t)(nt + n) * 768 + ct + tx] = f2bf(t[tx][n]);
  }
}

// ---- shared GEMM staging: 128x32 bf16 tiles, global_load_lds w=16, swizzled slots ----
// LDS linear [128][32]; 16B slot s of row holds k-chunk (s ^ (row&3)).
// Read side: fragment (row, kchunk lg) lives at slot lg ^ (row&3).
__device__ __forceinline__ void stage_tiles(const unsigned short* __restrict__ A,
                                            const unsigned short* __restrict__ Bt,
                                            unsigned short* lA, unsigned short* lB,
                                            int m0, int n0, int kt, int wave, int lane) {
#pragma unroll
  for (int i = 0; i < 2; ++i) {
    const int wl = wave + i * 4;              // wave-load 0..7, 16 rows each
    const int row = wl * 16 + (lane >> 2);
    const int kc = (lane & 3) ^ (row & 3);
    gl_lds16(A + (size_t)(m0 + row) * 768 + kt + kc * 8, lA + wl * 512);
    gl_lds16(Bt + (size_t)(n0 + row) * 768 + kt + kc * 8, lB + wl * 512);
  }
}

// ---------------- QKV GEMM: tokens(8192x768) @ w_qkv^T(768x2304) ----------------
__global__ __launch_bounds__(256) void qkv_gemm_kernel(const unsigned short* __restrict__ A,
                                                       const unsigned short* __restrict__ Bt,
                                                       unsigned short* __restrict__ Qo,
                                                       unsigned short* __restrict__ Ko,
                                                       unsigned short* __restrict__ Vt) {
  __shared__ unsigned short As[2][128 * 32];
  __shared__ unsigned short Bs[2][128 * 32];
  const int tid = threadIdx.x;
  const int wave = tid >> 6, lane = tid & 63;
  const int wr = wave >> 1, wc = wave & 1;
  const int lr = lane & 15, lg = lane >> 4;
  const int swk = lr & 3;
  const int m0 = blockIdx.y * 128, n0 = blockIdx.x * 128;

  f32x4 acc[4][4] = {};

  stage_tiles(A, Bt, As[0], Bs[0], m0, n0, 0, wave, lane);
  __syncthreads();

  for (int t = 0; t < 24; ++t) {
    const int cur = t & 1;
    if (t < 23)
      stage_tiles(A, Bt, As[cur ^ 1], Bs[cur ^ 1], m0, n0, (t + 1) * 32, wave, lane);
    s16x8 af[4], bf[4];
#pragma unroll
    for (int mi = 0; mi < 4; ++mi) {
      const int row = wr * 64 + mi * 16 + lr;
      af[mi] = *reinterpret_cast<const s16x8*>(&As[cur][row * 32 + ((lg ^ swk) * 8)]);
    }
#pragma unroll
    for (int ni = 0; ni < 4; ++ni) {
      const int row = wc * 64 + ni * 16 + lr;
      bf[ni] = *reinterpret_cast<const s16x8*>(&Bs[cur][row * 32 + ((lg ^ swk) * 8)]);
    }
#pragma unroll
    for (int mi = 0; mi < 4; ++mi)
#pragma unroll
      for (int ni = 0; ni < 4; ++ni)
        acc[mi][ni] = MFMA16(af[mi], bf[ni], acc[mi][ni]);
    __syncthreads();  // drains staged loads (vmcnt0) + frag reads; buffer swap safe
  }

#pragma unroll
  for (int ni = 0; ni < 4; ++ni) {
    const int col = n0 + wc * 64 + ni * 16 + lr;   // 0..2303
    const int t = col / 768;
    const int cc = col - t * 768;
    const int h = cc / 96;
    const int d = cc - h * 96;
#pragma unroll
    for (int mi = 0; mi < 4; ++mi) {
      const int gm = m0 + wr * 64 + mi * 16 + lg * 4;
      const int b = gm >> 10, n = gm & 1023;
      if (t == 2) {
        s16x4 v;
#pragma unroll
        for (int j = 0; j < 4; ++j) v[j] = (short)f2bf(acc[mi][ni][j]);
        *reinterpret_cast<s16x4*>(Vt + ((size_t)(b * 8 + h) * 96 + d) * 1024 + n) = v;
      } else {
        unsigned short* dst = (t == 0) ? Qo : Ko;
#pragma unroll
        for (int j = 0; j < 4; ++j)
          dst[((size_t)(b * 8 + h) * 1024 + n + j) * 96 + d] = f2bf(acc[mi][ni][j]);
      }
    }
  }
}

// ---------------- flash attention, in-register softmax ----------------
__global__ __launch_bounds__(512, 4) void attn_kernel(const unsigned short* __restrict__ Q,
                                                      const unsigned short* __restrict__ K,
                                                      const unsigned short* __restrict__ Vt,
                                                      unsigned short* __restrict__ Ao) {
  __shared__ unsigned short Ks[2][64][128];  // K rows padded 96->128 for XOR swizzle
  __shared__ unsigned short Vs[2][96][64];   // V^T rows: 64 kv = 8 slots

  const int f = blockIdx.x;
  const int xcd = f & 7;
  const int g = (f >> 3) + xcd * 64;   // same-bh blocks land on same XCD
  const int bh = g >> 3, qb = g & 7;

  const int tid = threadIdx.x, wave = tid >> 6, lane = tid & 63;
  const int lr = lane & 15, lg = lane >> 4;
  const int sw = lr & 7;  // read-side XOR swizzle key

  const unsigned short* Qp = Q + (size_t)bh * 1024 * 96;
  const unsigned short* Kp = K + (size_t)bh * 1024 * 96;
  const unsigned short* Vp = Vt + (size_t)bh * 96 * 1024;

  const int qrow = qb * 128 + wave * 16 + lr;
  s16x8 qreg[3];
#pragma unroll
  for (int kd = 0; kd < 3; ++kd)
    qreg[kd] = *reinterpret_cast<const s16x8*>(Qp + (size_t)qrow * 96 + kd * 32 + lg * 8);

  float m_r = -1e30f, l_r = 0.f;
  f32x4 oacc[6] = {};

  const int srcA = lr + ((lg & 1) << 5);
  const int srcB = srcA + 16;
  const bool hiT = (lg & 2) != 0;

#define STAGE(bufi, kv0)                                                              \
  {                                                                                   \
    _Pragma("unroll")                                                                 \
    for (int i = 0; i < 4; ++i) {                                                     \
      int cc = wave + 8 * i;                                                          \
      if (cc < 16) {                                                                  \
        int c = cc * 64 + lane;                                                       \
        int row = c >> 4, s = c & 15;                                                 \
        int sp = s ^ (row & 7);                                                       \
        if (sp > 11) sp = 11; /* pad slot, never read */                              \
        gl_lds16(Kp + (size_t)((kv0) + row) * 96 + sp * 8,                            \
                 &Ks[bufi][0][0] + cc * 512);                                         \
      } else if (cc < 28) {                                                           \
        int vc = cc - 16;                                                             \
        int c = vc * 64 + lane;                                                       \
        int row = c >> 3, s = c & 7;                                                  \
        int sp = s ^ (row & 7);                                                       \
        gl_lds16(Vp + (size_t)row * 1024 + (kv0) + sp * 8,                            \
                 &Vs[bufi][0][0] + vc * 512);                                         \
      }                                                                               \
    }                                                                                 \
  }

  STAGE(0, 0);
  __syncthreads();

  for (int gt = 0; gt < 16; ++gt) {
    const int buf = gt & 1;
    if (gt < 15) STAGE(buf ^ 1, (gt + 1) * 64);

    // ---- S^T = K Q^T over this 64-kv group ----
    f32x4 sacc[4] = {};
#pragma unroll
    for (int c = 0; c < 4; ++c) {
#pragma unroll
      for (int kd = 0; kd < 3; ++kd) {
        s16x8 kf = *reinterpret_cast<const s16x8*>(&Ks[buf][c * 16 + lr][((kd * 4 + lg) ^ sw) * 8]);
        sacc[c] = MFMA16(kf, qreg[kd], sacc[c]);
      }
    }

    // ---- online softmax (in-register; q = lr, kv lane-local) ----
    float mx = -1e30f;
#pragma unroll
    for (int c = 0; c < 4; ++c) {
#pragma unroll
      for (int j = 0; j < 4; ++j) {
        sacc[c][j] *= SCALE_F;
        mx = fmaxf(mx, sacc[c][j]);
      }
    }
    mx = fmaxf(mx, __shfl_xor(mx, 16));
    mx = fmaxf(mx, __shfl_xor(mx, 32));
    const float mNew = fmaxf(m_r, mx);
    const float rsc = __expf(m_r - mNew);
    float ts = 0.f;
    unsigned pk[4][2];
#pragma unroll
    for (int c = 0; c < 4; ++c) {
      float p0 = __expf(sacc[c][0] - mNew);
      float p1 = __expf(sacc[c][1] - mNew);
      float p2 = __expf(sacc[c][2] - mNew);
      float p3 = __expf(sacc[c][3] - mNew);
      ts += (p0 + p1) + (p2 + p3);
      pk[c][0] = pack_bf2(p0, p1);
      pk[c][1] = pack_bf2(p2, p3);
    }
    ts += __shfl_xor(ts, 16);
    ts += __shfl_xor(ts, 32);
    l_r = l_r * rsc + ts;
    m_r = mNew;
#pragma unroll
    for (int dt = 0; dt < 6; ++dt) oacc[dt] *= rsc;

    // ---- O^T += V^T P^T ----
#pragma unroll
    for (int gs = 0; gs < 2; ++gs) {
      const int t0 = gs * 2, t1 = t0 + 1;
      int la0 = __shfl((int)pk[t0][0], srcA), la1 = __shfl((int)pk[t1][0], srcA);
      int ha0 = __shfl((int)pk[t0][1], srcA), ha1 = __shfl((int)pk[t1][1], srcA);
      int lb0 = __shfl((int)pk[t0][0], srcB), lb1 = __shfl((int)pk[t1][0], srcB);
      int hb0 = __shfl((int)pk[t0][1], srcB), hb1 = __shfl((int)pk[t1][1], srcB);
      i32x4 bi;
      bi[0] = hiT ? la1 : la0;
      bi[1] = hiT ? ha1 : ha0;
      bi[2] = hiT ? lb1 : lb0;
      bi[3] = hiT ? hb1 : hb0;
      s16x8 pf = __builtin_bit_cast(s16x8, bi);
#pragma unroll
      for (int dt = 0; dt < 6; ++dt) {
        s16x8 vf = *reinterpret_cast<const s16x8*>(&Vs[buf][dt * 16 + lr][((gs * 4 + lg) ^ sw) * 8]);
        oacc[dt] = MFMA16(vf, pf, oacc[dt]);
      }
    }
    __syncthreads();  // drains staged loads; buffer swap safe
  }

  const float invl = 1.0f / l_r;
  const int b_ = bh >> 3, h_ = bh & 7;
  unsigned short* orow = Ao + (size_t)(b_ * 1024 + qrow) * 768 + h_ * 96;
#pragma unroll
  for (int dt = 0; dt < 6; ++dt) {
    s16x4 o4;
#pragma unroll
    for (int j = 0; j < 4; ++j) o4[j] = (short)f2bf(oacc[dt][j] * invl);
    *reinterpret_cast<s16x4*>(orow + dt * 16 + lg * 4) = o4;
  }
#undef STAGE
}

// ---------------- proj GEMM: attn(8192x768) @ w_proj^T + b, store transposed ----------------
__global__ __launch_bounds__(256) void proj_gemm_kernel(const unsigned short* __restrict__ A,
                                                        const unsigned short* __restrict__ Bt,
                                                        const float* __restrict__ bias,
                                                        float* __restrict__ out) {
  __shared__ unsigned short As[2][128 * 32];
  __shared__ unsigned short Bs[2][128 * 32];
  const int tid = threadIdx.x;
  const int wave = tid >> 6, lane = tid & 63;
  const int wr = wave >> 1, wc = wave & 1;
  const int lr = lane & 15, lg = lane >> 4;
  const int swk = lr & 3;
  const int m0 = blockIdx.y * 128, n0 = blockIdx.x * 128;

  f32x4 acc[4][4] = {};

  stage_tiles(A, Bt, As[0], Bs[0], m0, n0, 0, wave, lane);
  __syncthreads();

  for (int t = 0; t < 24; ++t) {
    const int cur = t & 1;
    if (t < 23)
      stage_tiles(A, Bt, As[cur ^ 1], Bs[cur ^ 1], m0, n0, (t + 1) * 32, wave, lane);
    s16x8 af[4], bf[4];
#pragma unroll
    for (int mi = 0; mi < 4; ++mi) {
      const int row = wr * 64 + mi * 16 + lr;
      af[mi] = *reinterpret_cast<const s16x8*>(&As[cur][row * 32 + ((lg ^ swk) * 8)]);
    }
#pragma unroll
    for (int ni = 0; ni < 4; ++ni) {
      const int row = wc * 64 + ni * 16 + lr;
      bf[ni] = *reinterpret_cast<const s16x8*>(&Bs[cur][row * 32 + ((lg ^ swk) * 8)]);
    }
#pragma unroll
    for (int mi = 0; mi < 4; ++mi)
#pragma unroll
      for (int ni = 0; ni < 4; ++ni)
        acc[mi][ni] = MFMA16(af[mi], bf[ni], acc[mi][ni]);
    __syncthreads();
  }

#pragma unroll
  for (int ni = 0; ni < 4; ++ni) {
    const int col = n0 + wc * 64 + ni * 16 + lr;  // c: 0..767
    const float bv = bias[col];
#pragma unroll
    for (int mi = 0; mi < 4; ++mi) {
      const int gm = m0 + wr * 64 + mi * 16 + lg * 4;
      const int b = gm >> 10, n = gm & 1023;
      f32x4 v;
#pragma unroll
      for (int j = 0; j < 4; ++j) v[j] = acc[mi][ni][j] + bv;
      *reinterpret_cast<f32x4*>(out + (size_t)b * 768 * 1024 + (size_t)col * 1024 + n) = v;
    }
  }
}

extern "C" void kernel_launch(void* const* d_in, const int* in_sizes, int n_in,
                              void* d_out, int out_size, void* d_ws, size_t ws_size,
                              hipStream_t stream) {
  const float* x = (const float*)d_in[0];
  const float* wqkv = (const float*)d_in[1];
  const float* wproj = (const float*)d_in[2];
  const float* bproj = (const float*)d_in[3];
  float* out = (float*)d_out;

  unsigned short* ws = (unsigned short*)d_ws;
  unsigned short* tokens = ws;                       // 8192*768
  unsigned short* wqkv_b = tokens + 8192 * 768;      // 2304*768
  unsigned short* wproj_b = wqkv_b + 2304 * 768;     // 768*768
  unsigned short* Qb = wproj_b + 768 * 768;          // [bh][1024][96]
  unsigned short* Kb = Qb + 64 * 1024 * 96;
  unsigned short* Vb = Kb + 64 * 1024 * 96;          // transposed [bh][96][1024]
  unsigned short* Ab = Vb + 64 * 1024 * 96;          // 8192*768

  cvt_bf16_kernel<<<1728, 256, 0, stream>>>(wqkv, wqkv_b, 2304 * 768 / 4);
  cvt_bf16_kernel<<<576, 256, 0, stream>>>(wproj, wproj_b, 768 * 768 / 4);
  transpose_x_kernel<<<dim3(24, 32, 8), dim3(32, 8), 0, stream>>>(x, tokens);
  qkv_gemm_kernel<<<dim3(18, 64), 256, 0, stream>>>(tokens, wqkv_b, Qb, Kb, Vb);
  attn_kernel<<<512, 512, 0, stream>>>(Qb, Kb, Vb, Ab);
  proj_gemm_kernel<<<dim3(6, 64), 256, 0, stream>>>(Ab, wproj_b, bproj, out);
}